// Round 8
// baseline (14058.076 us; speedup 1.0000x reference)
//
#include <hip/hip_runtime.h>
#include <hip/hip_bf16.h>

#define VSZ 128
#define EMBD 64
#define HSZ 512
#define BSZ 256
#define TLEN 512
#define NBLK 72              // 64 H (fused h0+h1, per rowgroup-quarter) + 8 FC

typedef __attribute__((ext_vector_type(8))) short short8;
typedef __attribute__((ext_vector_type(4))) float f32x4;
typedef __attribute__((ext_vector_type(4))) unsigned int u32x4;
typedef __hip_bfloat16 bf16;

#define SQ   ((size_t)HSZ*HSZ)

// ---- weight region (bf16 element offsets; layout identical to prior rounds) ----
#define O_WHH0HI ((size_t)0)
#define O_WHH0LO (O_WHH0HI + SQ)
#define O_WIH1HI (O_WHH0LO + SQ)
#define O_WIH1LO (O_WIH1HI + SQ)
#define O_WHH1HI (O_WIH1LO + SQ)
#define O_WHH1LO (O_WHH1HI + SQ)
#define O_WIH0HI (O_WHH1LO + SQ)                 // [N=512][K=64]
#define O_WIH0LO (O_WIH0HI + (size_t)HSZ*EMBD)
#define O_WFCHI  (O_WIH0LO + (size_t)HSZ*EMBD)   // [N=128][K=512]
#define O_WFCLO  (O_WFCHI + (size_t)VSZ*HSZ)
#define O_EMBHI  (O_WFCLO + (size_t)VSZ*HSZ)     // [128][64]
#define O_EMBLO  (O_EMBHI + (size_t)VSZ*EMBD)
// weights end at byte 3,571,712

// ---- rings: depth-3, u32-packed hi|lo, [16 rg][3 slot][4 q][16 row][128 col] ----
#define O_RINGB  ((size_t)3571712)
#define RGRING   (3*8192)                         // u32 per rowgroup (3 slots x 8192)
#define O_H0R_B  (O_RINGB)
#define O_H1R_B  (O_RINGB + (size_t)16*RGRING*4)
#define O_CTR_B  (O_H1R_B + (size_t)16*RGRING*4)  // counters x 256B
#define CTRN     224

#define ASTR   1024           // A-plane row stride bytes (swizzled)
#define SMEMSZ 65536

static __device__ __forceinline__ short8 ld8(const bf16* p) { return *(const short8*)p; }
static __device__ __forceinline__ float b2f(bf16 v) { return __bfloat162float(v); }
#define MFMA(a,b,c) __builtin_amdgcn_mfma_f32_16x16x32_bf16((a),(b),(c),0,0,0)

// ---- device-scope primitives (all loads wait inside their asm block) ----
static __device__ __forceinline__ void st4_sc(void* p, unsigned v) {
    asm volatile("global_store_dword %0, %1, off sc0 sc1" :: "v"(p), "v"(v) : "memory");
}
static __device__ __forceinline__ void st4i(int* p, int v) { st4_sc(p, (unsigned)v); }
static __device__ __forceinline__ void ld3x16sc(const unsigned* p0, const unsigned* p1,
                                                const unsigned* p2, u32x4* v) {
    asm volatile(
        "global_load_dwordx4 %0, %3, off sc0 sc1\n\t"
        "global_load_dwordx4 %1, %4, off sc0 sc1\n\t"
        "global_load_dwordx4 %2, %5, off sc0 sc1\n\t"
        "s_waitcnt vmcnt(0)"
        : "=&v"(v[0]), "=&v"(v[1]), "=&v"(v[2])
        : "v"(p0), "v"(p1), "v"(p2) : "memory");
}
static __device__ __forceinline__ void pref8sc(const unsigned* b1, const unsigned* b2,
                                               int tid, u32x4* v) {
    const unsigned* q0 = b1 + 0*2048 + tid*4; const unsigned* q1 = b1 + 1*2048 + tid*4;
    const unsigned* q2 = b1 + 2*2048 + tid*4; const unsigned* q3 = b1 + 3*2048 + tid*4;
    const unsigned* q4 = b2 + 0*2048 + tid*4; const unsigned* q5 = b2 + 1*2048 + tid*4;
    const unsigned* q6 = b2 + 2*2048 + tid*4; const unsigned* q7 = b2 + 3*2048 + tid*4;
    asm volatile(
        "global_load_dwordx4 %0, %8, off sc0 sc1\n\t"
        "global_load_dwordx4 %1, %9, off sc0 sc1\n\t"
        "global_load_dwordx4 %2, %10, off sc0 sc1\n\t"
        "global_load_dwordx4 %3, %11, off sc0 sc1\n\t"
        "global_load_dwordx4 %4, %12, off sc0 sc1\n\t"
        "global_load_dwordx4 %5, %13, off sc0 sc1\n\t"
        "global_load_dwordx4 %6, %14, off sc0 sc1\n\t"
        "global_load_dwordx4 %7, %15, off sc0 sc1\n\t"
        "s_waitcnt vmcnt(0)"
        : "=&v"(v[0]), "=&v"(v[1]), "=&v"(v[2]), "=&v"(v[3]),
          "=&v"(v[4]), "=&v"(v[5]), "=&v"(v[6]), "=&v"(v[7])
        : "v"(q0), "v"(q1), "v"(q2), "v"(q3), "v"(q4), "v"(q5), "v"(q6), "v"(q7)
        : "memory");
}
// per-lane poll: each active wave-0 lane spins on its own (ptr, need); exits together
static __device__ __forceinline__ void pollv(const int* p, int need, bool act, int wv) {
    if (wv == 0) {
        for (int it = 0; it < (1 << 17); ++it) {
            int ok = 1;
            if (act) {
                int v;
                asm volatile("global_load_dword %0, %1, off sc0 sc1\n\t"
                             "s_waitcnt vmcnt(0)" : "=v"(v) : "v"(p) : "memory");
                ok = (v >= need);
            }
            if (__all(ok)) break;
            __builtin_amdgcn_s_sleep(1);
        }
    }
    __syncthreads();
}
// unpack one u32x4 (4 packed cols of one row) into swizzled hi/lo A-planes
static __device__ __forceinline__ void awriteQ(char* Ahi, char* Alo, int tid,
                                               u32x4 v, int rowoff, int kbase) {
    int row = rowoff + (tid >> 5);
    int colb = kbase * 2 + (tid & 31) * 8;
    int off = row * ASTR + (colb ^ ((row & 7) << 4));
    uint2 hi, lo;
    hi.x = (v[0] & 0xffffu) | (v[1] << 16);  hi.y = (v[2] & 0xffffu) | (v[3] << 16);
    lo.x = (v[0] >> 16) | (v[1] & 0xffff0000u); lo.y = (v[2] >> 16) | (v[3] & 0xffff0000u);
    *(uint2*)(Ahi + off) = hi;
    *(uint2*)(Alo + off) = lo;
}

// ---- prep: split/transpose weights + zero counters ----
__global__ void k_prep(const float* __restrict__ emb, const float* __restrict__ Wih0,
                       const float* __restrict__ Whh0, const float* __restrict__ Wih1,
                       const float* __restrict__ Whh1, const float* __restrict__ Wfc,
                       bf16* __restrict__ ws) {
    int j = blockIdx.x * blockDim.x + threadIdx.x;
    const int SQi = HSZ * HSZ;
    if (j < SQi) {
        int n = j / HSZ, k = j - n * HSZ;
        float w = Whh0[k * HSZ + n];
        bf16 hi = __float2bfloat16(w);
        ws[O_WHH0HI + j] = hi; ws[O_WHH0LO + j] = __float2bfloat16(w - b2f(hi));
        return;
    }
    j -= SQi;
    if (j < SQi) {
        int n = j / HSZ, k = j - n * HSZ;
        float w = Wih1[k * HSZ + n];
        bf16 hi = __float2bfloat16(w);
        ws[O_WIH1HI + j] = hi; ws[O_WIH1LO + j] = __float2bfloat16(w - b2f(hi));
        return;
    }
    j -= SQi;
    if (j < SQi) {
        int n = j / HSZ, k = j - n * HSZ;
        float w = Whh1[k * HSZ + n];
        bf16 hi = __float2bfloat16(w);
        ws[O_WHH1HI + j] = hi; ws[O_WHH1LO + j] = __float2bfloat16(w - b2f(hi));
        return;
    }
    j -= SQi;
    if (j < HSZ * EMBD) {
        int n = j / EMBD, k = j - n * EMBD;
        float w = Wih0[k * HSZ + n];
        bf16 hi = __float2bfloat16(w);
        ws[O_WIH0HI + j] = hi; ws[O_WIH0LO + j] = __float2bfloat16(w - b2f(hi));
        return;
    }
    j -= HSZ * EMBD;
    if (j < VSZ * HSZ) {
        int n = j / HSZ, k = j - n * HSZ;
        float w = Wfc[k * VSZ + n];
        bf16 hi = __float2bfloat16(w);
        ws[O_WFCHI + j] = hi; ws[O_WFCLO + j] = __float2bfloat16(w - b2f(hi));
        return;
    }
    j -= VSZ * HSZ;
    if (j < VSZ * EMBD) {
        float w = emb[j];
        bf16 hi = __float2bfloat16(w);
        ws[O_EMBHI + j] = hi; ws[O_EMBLO + j] = __float2bfloat16(w - b2f(hi));
        return;
    }
    j -= VSZ * EMBD;
    if (j < CTRN * 64) ((int*)((char*)ws + O_CTR_B))[j] = 0;
}

// ---- persistent fused pipeline: H (h0 phase -> mid exchange -> h1 phase) + FC ----
__global__ __launch_bounds__(512, 1) void k_persist(
    const int* __restrict__ x,
    const float* __restrict__ bih0, const float* __restrict__ bhh0,
    const float* __restrict__ bih1, const float* __restrict__ bhh1,
    const float* __restrict__ bfc,
    bf16* __restrict__ ws, float* __restrict__ out)
{
    extern __shared__ char smem[];
    const int tid = (int)threadIdx.x;
    const int lane = tid & 63;
    const int wv   = tid >> 6;
    const int l15  = lane & 15;
    const int quad = lane >> 4;
    const int bid  = (int)blockIdx.x;
    const int swz  = (l15 & 7) << 4;

    int* CTR = (int*)((char*)ws + O_CTR_B);
#define HP0(i)  (CTR + (size_t)(i) * 64)          // h0 quarter published
#define HPR(i)  (CTR + (size_t)(64 + (i)) * 64)   // h1 quarter published (step done)
#define FCC(f)  (CTR + (size_t)(128 + (f)) * 64)  // FC consumed h1[t]
#define H0R(rg) ((unsigned*)((char*)ws + O_H0R_B) + (size_t)(rg)*RGRING)
#define H1R(rg) ((unsigned*)((char*)ws + O_H1R_B) + (size_t)(rg)*RGRING)

    if (bid < 64) {
        // ==== H(rg,q): h0[t] quarter then h1[t] quarter; state planes persistent in LDS ====
        const int rg = bid >> 2, q = bid & 3, mb = rg * 16, qcb = q * 128;
        char* A0hi = smem;              // h0 full-row planes [16][512] (swizzled)
        char* A0lo = smem + 16384;
        char* A1hi = smem + 32768;      // h1 full-row planes
        char* A1lo = smem + 49152;
        const bf16* embhi = ws + O_EMBHI; const bf16* emblo = ws + O_EMBLO;
        const int col = qcb + wv * 16 + l15;
        const float b0 = bih0[col] + bhh0[col];
        const float b1 = bih1[col] + bhh1[col];
        const bf16* w0h = ws + O_WHH0HI + (size_t)col * HSZ + quad * 8;   // Whh0
        const bf16* w0l = ws + O_WHH0LO + (size_t)col * HSZ + quad * 8;
        const bf16* e0h = ws + O_WIH0HI + (size_t)col * EMBD + quad * 8;  // Wih0
        const bf16* e0l = ws + O_WIH0LO + (size_t)col * EMBD + quad * 8;
        const bf16* w1h = ws + O_WIH1HI + (size_t)col * HSZ + quad * 8;   // Wih1
        const bf16* w1l = ws + O_WIH1LO + (size_t)col * HSZ + quad * 8;
        const bf16* whh = ws + O_WHH1HI + (size_t)col * HSZ + quad * 8;   // Whh1
        const bf16* whl = ws + O_WHH1LO + (size_t)col * HSZ + quad * 8;
        unsigned* h0r = H0R(rg);
        unsigned* h1r = H1R(rg);
        const int qa = (q + 1) & 3, qb2 = (q + 2) & 3, qc = (q + 3) & 3;
        const int f = rg >> 1;
        const int sib0 = rg * 4 + qa, sib1 = rg * 4 + qb2, sib2 = rg * 4 + qc;

        for (int i = tid * 4; i < 65536; i += 2048) *(unsigned*)(smem + i) = 0u; // h[-1]=0
        __syncthreads();

        for (int t = 0; t < TLEN; ++t) {
            const int sc_ = t % 3;               // slot for step t
            const int sp_ = (t + 2) % 3;         // slot for step t-1
            // ---- TOP poll: sibs finished step t-1 (h1[t-1] published); FC done with t-3 ----
            const int* pp = nullptr; int nd = 0; bool act = false;
            if (wv == 0) {
                if (lane == 0)      { pp = HPR(sib0); nd = t; act = (t > 0); }
                else if (lane == 1) { pp = HPR(sib1); nd = t; act = (t > 0); }
                else if (lane == 2) { pp = HPR(sib2); nd = t; act = (t > 0); }
                else if (lane == 3) { pp = FCC(f);    nd = t - 2; act = (t >= 3); }
            }
            pollv(pp, nd, act, wv);
            // ---- stage h1[t-1] sibling quarters into A1 ----
            if (t > 0) {
                const unsigned* sl = h1r + (size_t)sp_ * 8192;
                u32x4 v3[3];
                ld3x16sc(sl + qa*2048 + tid*4, sl + qb2*2048 + tid*4, sl + qc*2048 + tid*4, v3);
                awriteQ(A1hi, A1lo, tid, v3[0], 0, qa * 128);
                awriteQ(A1hi, A1lo, tid, v3[1], 0, qb2 * 128);
                awriteQ(A1hi, A1lo, tid, v3[2], 0, qc * 128);
            }
            // per-lane emb gather (row = l15) straight to registers
            const int xr = x[(size_t)(mb + l15) * TLEN + t];
            short8 eh0 = ld8(embhi + (size_t)xr * EMBD + quad * 8);
            short8 el0 = ld8(emblo + (size_t)xr * EMBD + quad * 8);
            short8 eh1 = ld8(embhi + (size_t)xr * EMBD + 32 + quad * 8);
            short8 el1 = ld8(emblo + (size_t)xr * EMBD + 32 + quad * 8);
            __syncthreads();
            // ---- kloop h0: emb@Wih0 (K=64) + A0(h0[t-1])@Whh0 (K=512) ----
            f32x4 aA = {}, aB = {};
            {
                short8 bh = ld8(e0h), bl = ld8(e0l);
                aA = MFMA(eh0, bh, aA); aB = MFMA(el0, bh, aB); aB = MFMA(eh0, bl, aB);
                bh = ld8(e0h + 32); bl = ld8(e0l + 32);
                aA = MFMA(eh1, bh, aA); aB = MFMA(el1, bh, aB); aB = MFMA(eh1, bl, aB);
            }
#pragma unroll
            for (int kc = 0; kc < 16; kc++) {
                int aoff = l15 * ASTR + ((kc * 64 + quad * 16) ^ swz);
                short8 ah = *(const short8*)(A0hi + aoff);
                short8 al = *(const short8*)(A0lo + aoff);
                short8 bh = ld8(w0h + kc * 32);
                short8 bl = ld8(w0l + kc * 32);
                aA = MFMA(ah, bh, aA); aB = MFMA(al, bh, aB); aB = MFMA(ah, bl, aB);
            }
            __syncthreads();                 // all A0 reads done before own-quarter overwrite
            // ---- h0 epilogue: tanh -> own A0 quarter + h0 ring ----
            unsigned* slot0 = h0r + (size_t)sc_ * 8192 + q * 2048;
#pragma unroll
            for (int rr = 0; rr < 4; rr++) {
                int row = quad * 4 + rr;
                float v = tanhf(aA[rr] + aB[rr] + b0);
                bf16 hb = __float2bfloat16(v);
                bf16 lb = __float2bfloat16(v - b2f(hb));
                unsigned short hu, lu;
                __builtin_memcpy(&hu, &hb, 2); __builtin_memcpy(&lu, &lb, 2);
                int loff = row * ASTR + ((col * 2) ^ ((row & 7) << 4));
                *(unsigned short*)(A0hi + loff) = hu;
                *(unsigned short*)(A0lo + loff) = lu;
                st4_sc(slot0 + (size_t)row * 128 + wv * 16 + l15,
                       (unsigned)hu | ((unsigned)lu << 16));
            }
            asm volatile("s_waitcnt vmcnt(0)" ::: "memory");
            __syncthreads();
            if (tid == 0) st4i(HP0(rg * 4 + q), t + 1);
            // ---- MID poll: sibling h0[t] quarters published ----
            pp = nullptr; nd = 0; act = false;
            if (wv == 0) {
                if (lane == 0)      { pp = HP0(sib0); nd = t + 1; act = true; }
                else if (lane == 1) { pp = HP0(sib1); nd = t + 1; act = true; }
                else if (lane == 2) { pp = HP0(sib2); nd = t + 1; act = true; }
            }
            pollv(pp, nd, act, wv);
            {   // dual-use load: feeds h1[t] now, h0[t+1] next step
                const unsigned* sl = h0r + (size_t)sc_ * 8192;
                u32x4 v3[3];
                ld3x16sc(sl + qa*2048 + tid*4, sl + qb2*2048 + tid*4, sl + qc*2048 + tid*4, v3);
                awriteQ(A0hi, A0lo, tid, v3[0], 0, qa * 128);
                awriteQ(A0hi, A0lo, tid, v3[1], 0, qb2 * 128);
                awriteQ(A0hi, A0lo, tid, v3[2], 0, qc * 128);
            }
            __syncthreads();
            // ---- kloop h1: A1(h1[t-1])@Whh1 then A0(h0[t])@Wih1 ----
            f32x4 cA = {}, cB = {};
#pragma unroll
            for (int kc = 0; kc < 16; kc++) {
                int aoff = l15 * ASTR + ((kc * 64 + quad * 16) ^ swz);
                short8 ah = *(const short8*)(A1hi + aoff);
                short8 al = *(const short8*)(A1lo + aoff);
                short8 bh = ld8(whh + kc * 32);
                short8 bl = ld8(whl + kc * 32);
                cA = MFMA(ah, bh, cA); cB = MFMA(al, bh, cB); cB = MFMA(ah, bl, cB);
            }
#pragma unroll
            for (int kc = 0; kc < 16; kc++) {
                int aoff = l15 * ASTR + ((kc * 64 + quad * 16) ^ swz);
                short8 ah = *(const short8*)(A0hi + aoff);
                short8 al = *(const short8*)(A0lo + aoff);
                short8 bh = ld8(w1h + kc * 32);
                short8 bl = ld8(w1l + kc * 32);
                cA = MFMA(ah, bh, cA); cB = MFMA(al, bh, cB); cB = MFMA(ah, bl, cB);
            }
            __syncthreads();                 // all A1 reads done before own-quarter overwrite
            // ---- h1 epilogue: tanh -> own A1 quarter + h1 ring ----
            unsigned* slot1 = h1r + (size_t)sc_ * 8192 + q * 2048;
#pragma unroll
            for (int rr = 0; rr < 4; rr++) {
                int row = quad * 4 + rr;
                float v = tanhf(cA[rr] + cB[rr] + b1);
                bf16 hb = __float2bfloat16(v);
                bf16 lb = __float2bfloat16(v - b2f(hb));
                unsigned short hu, lu;
                __builtin_memcpy(&hu, &hb, 2); __builtin_memcpy(&lu, &lb, 2);
                int loff = row * ASTR + ((col * 2) ^ ((row & 7) << 4));
                *(unsigned short*)(A1hi + loff) = hu;
                *(unsigned short*)(A1lo + loff) = lu;
                st4_sc(slot1 + (size_t)row * 128 + wv * 16 + l15,
                       (unsigned)hu | ((unsigned)lu << 16));
            }
            asm volatile("s_waitcnt vmcnt(0)" ::: "memory");
            __syncthreads();
            if (tid == 0) st4i(HPR(rg * 4 + q), t + 1);
        }

    } else {
        // ==== FC(f): logits[32 rows, t, 128] = h1[t] @ Wfc + b (off critical path) ====
        const int f = bid - 64, mb = f * 32;
        char* FAhi = smem;            // 32-row planes
        char* FAlo = smem + 32768;
        const int col = wv * 16 + l15;
        const float bias = bfc[col];
        const bf16* wfh = ws + O_WFCHI + (size_t)col * HSZ + quad * 8;
        const bf16* wfl = ws + O_WFCLO + (size_t)col * HSZ + quad * 8;
        const unsigned* r1 = H1R(2 * f);
        const unsigned* r2 = H1R(2 * f + 1);

        for (int t = 0; t < TLEN; ++t) {
            const int sc_ = t % 3;
            // poll: 8 H producers (2 rgs x 4 quarters) finished step t
            const int* pp = nullptr; int nd = 0; bool act = false;
            if (wv == 0 && lane < 8) {
                pp = HPR((2 * f + (lane >> 2)) * 4 + (lane & 3)); nd = t + 1; act = true;
            }
            pollv(pp, nd, act, wv);
            u32x4 pf[8];
            pref8sc(r1 + (size_t)sc_ * 8192, r2 + (size_t)sc_ * 8192, tid, pf);
#pragma unroll
            for (int i = 0; i < 8; i++)
                awriteQ(FAhi, FAlo, tid, pf[i], (i >> 2) * 16, (i & 3) * 128);
            __syncthreads();
            if (tid == 0) st4i(FCC(f), t + 1);             // release h1[t] slot
            f32x4 accA[2] = {}, accB[2] = {};
#pragma unroll
            for (int kc = 0; kc < 16; kc++) {
                short8 bh = ld8(wfh + kc * 32);
                short8 bl = ld8(wfl + kc * 32);
#pragma unroll
                for (int mi = 0; mi < 2; mi++) {
                    int aoff = (mi * 16 + l15) * ASTR + ((kc * 64 + quad * 16) ^ swz);
                    short8 ah = *(const short8*)(FAhi + aoff);
                    short8 al = *(const short8*)(FAlo + aoff);
                    accA[mi] = MFMA(ah, bh, accA[mi]);
                    accB[mi] = MFMA(al, bh, accB[mi]);
                    accB[mi] = MFMA(ah, bl, accB[mi]);
                }
            }
#pragma unroll
            for (int mi = 0; mi < 2; mi++)
#pragma unroll
                for (int rr = 0; rr < 4; rr++) {
                    int row = mb + mi * 16 + quad * 4 + rr;
                    out[((size_t)row * TLEN + t) * VSZ + col] = accA[mi][rr] + accB[mi][rr] + bias;
                }
        }
    }
#undef HP0
#undef HPR
#undef FCC
#undef H0R
#undef H1R
}

extern "C" void kernel_launch(void* const* d_in, const int* in_sizes, int n_in,
                              void* d_out, int out_size, void* d_ws, size_t ws_size,
                              hipStream_t stream) {
    const int*   x    = (const int*)d_in[0];
    const float* emb  = (const float*)d_in[1];
    const float* Wih0 = (const float*)d_in[2];
    const float* bih0 = (const float*)d_in[3];
    const float* Whh0 = (const float*)d_in[4];
    const float* bhh0 = (const float*)d_in[5];
    const float* Wih1 = (const float*)d_in[6];
    const float* bih1 = (const float*)d_in[7];
    const float* Whh1 = (const float*)d_in[8];
    const float* bhh1 = (const float*)d_in[9];
    const float* Wfc  = (const float*)d_in[10];
    const float* bfc  = (const float*)d_in[11];
    float* out = (float*)d_out;
    bf16* ws   = (bf16*)d_ws;

    const int total = 3 * HSZ * HSZ + HSZ * EMBD + VSZ * HSZ + VSZ * EMBD + CTRN * 64;
    k_prep<<<(total + 255) / 256, 256, 0, stream>>>(emb, Wih0, Whh0, Wih1, Whh1, Wfc, ws);

    k_persist<<<NBLK, 512, SMEMSZ, stream>>>(x, bih0, bhh0, bih1, bhh1, bfc, ws, out);
}